// Round 9
// baseline (121.684 us; speedup 1.0000x reference)
//
#include <hip/hip_runtime.h>
#include <math.h>

#define V 8
#define B 128
#define P 512
#define NE 75

static constexpr float NU = 0.1f;
static constexpr float EPS = 1e-5f;
static constexpr float INV_SQRT2 = 0.70710678118654752440f;
static constexpr float L2E = 1.4426950408889634f;  // log2(e)

typedef float v4f __attribute__((ext_vector_type(4)));

__device__ __forceinline__ float fast_exp2(float x) {
#if __has_builtin(__builtin_amdgcn_exp2f)
  return __builtin_amdgcn_exp2f(x);
#else
  return exp2f(x);
#endif
}

__device__ __forceinline__ v4f v4fma(v4f a, v4f b, v4f c) {
#if __has_builtin(__builtin_elementwise_fma)
  return __builtin_elementwise_fma(a, b, c);
#else
  v4f r;
  r.x = fmaf(a.x, b.x, c.x); r.y = fmaf(a.y, b.y, c.y);
  r.z = fmaf(a.z, b.z, c.z); r.w = fmaf(a.w, b.w, c.w);
  return r;
#endif
}

// ---------------------------------------------------------------------------
// KA (hot, fused): transform + masked Gaussian structure sums + conv1d(3->16)
//                  -> conv1d(16->4) -> channel-max -> l1(75->25)
// One block per (i,b), 256 threads. (Unchanged from R8.)
// Hot loop: 4 ds_read_b128 + 16 pk_fma + 8 exp2 + 8 add per 8 points;
// wave-uniform-j mapping -> single-address broadcast LDS reads; masked
// points staged as 1e9 -> exp2 -> 0 exactly.
// ---------------------------------------------------------------------------
__global__ __launch_bounds__(256, 4) void k_structure(
    const float2* __restrict__ pts2,      // [V,B,P] (birth,death)
    const int* __restrict__ lengths,      // [V,B]
    const float* __restrict__ centers,    // [V,NE,2] (transformed)
    const float* __restrict__ sharp,      // [V,NE,2]
    const float* __restrict__ c1w,        // [V,16,3]
    const float* __restrict__ c2w,        // [V,4,16]
    const float* __restrict__ l1w,        // [V,25,NE]
    const float* __restrict__ l1b,        // [V,25]
    float* __restrict__ A1t) {            // [V*25][B]
  int i = blockIdx.x >> 7;
  int b = blockIdx.x & 127;
  int t = threadIdx.x;

  __shared__ float sS[3][P], sY[3][P];    // 12 KB SoA (s,y only)
  __shared__ float slb[3][NE];
  __shared__ float hn[NE];

  int d0 = (i + V - 1) & (V - 1), d1 = i, d2 = (i + 1) & (V - 1);
  int len0 = lengths[d0 * B + b];
  int len1 = lengths[d1 * B + b];
  int len2 = lengths[d2 * B + b];

  for (int u = t; u < 3 * P; u += 256) {
    int jj = u >> 9;
    int pp = u & (P - 1);
    int d   = (jj == 0) ? d0 : (jj == 1) ? d1 : d2;
    int len = (jj == 0) ? len0 : (jj == 1) ? len1 : len2;
    float2 q = pts2[((size_t)d * B + b) * P + pp];
    float s = (q.x + q.y) * INV_SQRT2;
    float y = (q.y - q.x) * INV_SQRT2;
    if (y <= NU) y = __logf(fmaxf(y, 1e-12f) * 10.0f) + NU;
    if (pp >= len) { s = 1e9f; y = 1e9f; }  // exp2 -> 0 exactly
    sS[jj][pp] = s;
    sY[jj][pp] = y;
  }

  // wave-uniform (j,n) mapping
  int w = t >> 6, l = t & 63;
  int j, n;
  bool active;
  if (w < 3) {
    j = w;
    n = l;
    active = true;
  } else {
    active = (l < 33);
    int jl = l / 11;
    if (!active) jl = 2;
    j = jl;
    n = active ? (64 + (l - jl * 11)) : 74;
  }

  int ci = (i * NE + n) * 2;
  float a  = sharp[ci],   c  = sharp[ci + 1];
  float cs = centers[ci], cy = centers[ci + 1];
  float nA = -a * L2E;
  float nC = -c * L2E;
  float Bsc = 2.0f * a * cs * L2E;
  float Byc = 2.0f * c * cy * L2E;
  float nD = -(a * cs * cs + c * cy * cy) * L2E;
  v4f nA4 = {nA, nA, nA, nA}, nC4 = {nC, nC, nC, nC};
  v4f Bs4 = {Bsc, Bsc, Bsc, Bsc}, By4 = {Byc, Byc, Byc, Byc};
  v4f nD4 = {nD, nD, nD, nD};

  int mx = (w == 0) ? len0
         : (w == 1) ? len1
         : (w == 2) ? len2 : max(len0, max(len1, len2));
  int trip = (mx + 7) & ~7;

  __syncthreads();

  float ac0 = 0.f, ac1 = 0.f, ac2 = 0.f, ac3 = 0.f;
  float ac4 = 0.f, ac5 = 0.f, ac6 = 0.f, ac7 = 0.f;
  for (int p = 0; p < trip; p += 8) {
    v4f Sa = *(const v4f*)&sS[j][p], Sb = *(const v4f*)&sS[j][p + 4];
    v4f Ya = *(const v4f*)&sY[j][p], Yb = *(const v4f*)&sY[j][p + 4];
    v4f ua = v4fma(nA4, Sa, Bs4), ub = v4fma(nA4, Sb, Bs4);
    v4f va = v4fma(nC4, Ya, By4), vb = v4fma(nC4, Yb, By4);
    v4f ta = v4fma(Sa, ua, nD4),  tb = v4fma(Sb, ub, nD4);
    v4f argA = v4fma(Ya, va, ta), argB = v4fma(Yb, vb, tb);
    ac0 += fast_exp2(argA.x);
    ac1 += fast_exp2(argA.y);
    ac2 += fast_exp2(argA.z);
    ac3 += fast_exp2(argA.w);
    ac4 += fast_exp2(argB.x);
    ac5 += fast_exp2(argB.y);
    ac6 += fast_exp2(argB.z);
    ac7 += fast_exp2(argB.w);
  }
  float accv = ((ac0 + ac1) + (ac2 + ac3)) + ((ac4 + ac5) + (ac6 + ac7));

  if (active) slb[j][n] = accv;
  __syncthreads();

  if (t < NE) {
    float s0 = slb[0][t], s1 = slb[1][t], s2 = slb[2][t];
    float a0 = 0, a1 = 0, a2 = 0, a3 = 0;
#pragma unroll
    for (int f = 0; f < 16; ++f) {
      float w0 = c1w[(i * 16 + f) * 3 + 0];
      float w1 = c1w[(i * 16 + f) * 3 + 1];
      float w2 = c1w[(i * 16 + f) * 3 + 2];
      float h1 = fmaf(w0, s0, fmaf(w1, s1, w2 * s2));
      a0 = fmaf(c2w[(i * 4 + 0) * 16 + f], h1, a0);
      a1 = fmaf(c2w[(i * 4 + 1) * 16 + f], h1, a1);
      a2 = fmaf(c2w[(i * 4 + 2) * 16 + f], h1, a2);
      a3 = fmaf(c2w[(i * 4 + 3) * 16 + f], h1, a3);
    }
    hn[t] = fmaxf(fmaxf(a0, a1), fmaxf(a2, a3));
  }
  __syncthreads();

  if (t < 25) {
    float acc = l1b[i * 25 + t];
    const float* wgt = l1w + ((size_t)i * 25 + t) * NE;
#pragma unroll 5
    for (int m = 0; m < NE; ++m) acc = fmaf(wgt[m], hn[m], acc);
    A1t[((size_t)(i * 25 + t)) * B + b] = acc;
  }
}

// ---------------------------------------------------------------------------
// KB (merged tails): bn1 + l2 + relu + fc1, then LAST-BLOCK-TAKES-OVER for
// bn2 + fc2 (replaces the third kernel launch).
//
// Last-block pattern (deadlock-free, no spinning, dispatch-order-agnostic):
// every block: write Yt column -> __threadfence (agent release) ->
// __syncthreads -> t0 atomicAdd(counter). The block seeing
// old & 127 == 127 knows all 128 blocks' Yt stores are visible (their
// fences precede their increments), acquires, and computes bn2+fc2 for all
// b. Counter is monotonic: trigger = mod-128 condition, so it fires exactly
// once per replay with NO re-initialization (graph-replay-safe even from
// the 0xAAAAAAAA poison value).
// ---------------------------------------------------------------------------
__global__ __launch_bounds__(256) void k_tail12(
    const float* __restrict__ A1t, const float* __restrict__ g1,
    const float* __restrict__ b1, const float* __restrict__ l2w,
    const float* __restrict__ l2b, const float* __restrict__ fc1w,
    const float* __restrict__ fc1b, const float* __restrict__ g2,
    const float* __restrict__ b2, const float* __restrict__ fc2w,
    const float* __restrict__ fc2b, float* __restrict__ Yt,
    unsigned int* __restrict__ cnt, float* __restrict__ out) {
  int b = blockIdx.x;
  int t = threadIdx.x;
  __shared__ float xin[200];
  __shared__ float Xl[200];
  __shared__ float yn[100][128];   // 51.2 KB, used only by the trigger block
  __shared__ int isLast;

  // ---- bn1 (redundant per-block batch stats from L2) ----
  if (t < 200) {
    const float4* col = (const float4*)(A1t + (size_t)t * B);
    float4 s4 = {0, 0, 0, 0}, q4 = {0, 0, 0, 0};
#pragma unroll
    for (int u = 0; u < B / 4; ++u) {
      float4 v = col[u];
      s4.x += v.x; s4.y += v.y; s4.z += v.z; s4.w += v.w;
      q4.x = fmaf(v.x, v.x, q4.x); q4.y = fmaf(v.y, v.y, q4.y);
      q4.z = fmaf(v.z, v.z, q4.z); q4.w = fmaf(v.w, v.w, q4.w);
    }
    float s = (s4.x + s4.y) + (s4.z + s4.w);
    float q = (q4.x + q4.y) + (q4.z + q4.w);
    float m = s * (1.0f / B);
    float var = q * (1.0f / B) - m * m;
    float r = rsqrtf(var + EPS);
    float v = A1t[(size_t)t * B + b];
    xin[t] = (v - m) * r * g1[t] + b1[t];
  }
  __syncthreads();
  // ---- l2 + relu ----
  if (t < 200) {
    int i = t / 25;
    float acc = l2b[t];
    const float* w = l2w + (size_t)t * 25;
    const float* x = xin + i * 25;
#pragma unroll
    for (int jj = 0; jj < 25; ++jj) acc = fmaf(w[jj], x[jj], acc);
    Xl[t] = fmaxf(acc, 0.0f);
  }
  __syncthreads();
  // ---- fc1 -> Yt[f][b] ----
  if (t < 100) {
    float acc = fc1b[t];
    const float* w = fc1w + (size_t)t * 200;
#pragma unroll 8
    for (int q = 0; q < 200; ++q) acc = fmaf(w[q], Xl[q], acc);
    Yt[(size_t)t * B + b] = acc;
  }

  // ---- release + arrive ----
  __threadfence();              // own Yt stores -> agent-visible
  __syncthreads();              // all lanes' fences complete before t0's add
  if (t == 0) {
    unsigned int old = atomicAdd(cnt, 1u);
    isLast = ((old & 127u) == 127u) ? 1 : 0;
  }
  __syncthreads();
  if (!isLast) return;

  // ---- trigger block: bn2 + fc2 for ALL b ----
  __threadfence();              // acquire: see all blocks' Yt
  if (t < 100) {
    const float* row = Yt + (size_t)t * B;
    float s = 0.f, q = 0.f;
#pragma unroll 8
    for (int u = 0; u < B; ++u) {
      float v = row[u];
      s += v;
      q = fmaf(v, v, q);
    }
    float m = s * (1.0f / B);
    float var = q * (1.0f / B) - m * m;
    float r = rsqrtf(var + EPS);
    float gg = g2[t], bb = b2[t];
    for (int u = 0; u < B; ++u)
      yn[t][u] = (row[u] - m) * r * gg + bb;
  }
  __syncthreads();
  // fc2: thread t handles column b = t&127, outputs o = (t>>7)*35 .. +34
  {
    int bb = t & 127;
    int o0 = (t >> 7) * 35;
    for (int oo = 0; oo < 35; ++oo) {
      int o = o0 + oo;
      float acc = fc2b[o];
      const float* w = fc2w + (size_t)o * 100;
#pragma unroll 4
      for (int f = 0; f < 100; ++f) acc = fmaf(w[f], yn[f][bb], acc);
      out[(size_t)bb * 70 + o] = acc;
    }
  }
}

// ---------------------------------------------------------------------------
extern "C" void kernel_launch(void* const* d_in, const int* in_sizes, int n_in,
                              void* d_out, int out_size, void* d_ws, size_t ws_size,
                              hipStream_t stream) {
  const float2* pts2   = (const float2*)d_in[0];
  const int*   lengths = (const int*)d_in[1];
  const float* centers = (const float*)d_in[2];
  const float* sharp   = (const float*)d_in[3];
  const float* c1w     = (const float*)d_in[4];
  const float* c2w     = (const float*)d_in[5];
  const float* l1w     = (const float*)d_in[6];
  const float* l1b     = (const float*)d_in[7];
  const float* bn1g    = (const float*)d_in[8];
  const float* bn1b    = (const float*)d_in[9];
  const float* l2w     = (const float*)d_in[10];
  const float* l2b     = (const float*)d_in[11];
  const float* fc1w    = (const float*)d_in[12];
  const float* fc1b    = (const float*)d_in[13];
  const float* fbn_g   = (const float*)d_in[14];
  const float* fbn_b   = (const float*)d_in[15];
  const float* fc2w    = (const float*)d_in[16];
  const float* fc2b    = (const float*)d_in[17];
  float* out = (float*)d_out;

  float* A1t = (float*)d_ws;                    // [200][128]
  float* Yt  = A1t + 200 * B;                   // [100][128]
  unsigned int* cnt = (unsigned int*)(Yt + 100 * B);  // monotonic counter

  k_structure<<<dim3(V * B), dim3(256), 0, stream>>>(
      pts2, lengths, centers, sharp, c1w, c2w, l1w, l1b, A1t);
  k_tail12<<<dim3(B), dim3(256), 0, stream>>>(
      A1t, bn1g, bn1b, l2w, l2b, fc1w, fc1b, fbn_g, fbn_b, fc2w, fc2b,
      Yt, cnt, out);
}

// Round 10
// 68.256 us; speedup vs baseline: 1.7828x; 1.7828x over previous
//
#include <hip/hip_runtime.h>
#include <math.h>

#define V 8
#define B 128
#define P 512
#define NE 75

static constexpr float NU = 0.1f;
static constexpr float EPS = 1e-5f;
static constexpr float INV_SQRT2 = 0.70710678118654752440f;
static constexpr float L2E = 1.4426950408889634f;  // log2(e)

typedef float v4f __attribute__((ext_vector_type(4)));

__device__ __forceinline__ float fast_exp2(float x) {
#if __has_builtin(__builtin_amdgcn_exp2f)
  return __builtin_amdgcn_exp2f(x);
#else
  return exp2f(x);
#endif
}

__device__ __forceinline__ v4f v4fma(v4f a, v4f b, v4f c) {
#if __has_builtin(__builtin_elementwise_fma)
  return __builtin_elementwise_fma(a, b, c);
#else
  v4f r;
  r.x = fmaf(a.x, b.x, c.x); r.y = fmaf(a.y, b.y, c.y);
  r.z = fmaf(a.z, b.z, c.z); r.w = fmaf(a.w, b.w, c.w);
  return r;
#endif
}

// ---------------------------------------------------------------------------
// ROUND-10: MEASUREMENT ROUND. Identical kernels to R8 (best-known: 44.16us),
// but k_structure is launched TWICE (idempotent: rewrites identical A1t).
// Delta vs R8 total = k_structure duration + 1 launch overhead. This pins
// down where the unaccounted ~30us lives (in-kernel vs harness floor).
// ---------------------------------------------------------------------------
__global__ __launch_bounds__(256, 4) void k_structure(
    const float2* __restrict__ pts2,      // [V,B,P] (birth,death)
    const int* __restrict__ lengths,      // [V,B]
    const float* __restrict__ centers,    // [V,NE,2] (transformed)
    const float* __restrict__ sharp,      // [V,NE,2]
    const float* __restrict__ c1w,        // [V,16,3]
    const float* __restrict__ c2w,        // [V,4,16]
    const float* __restrict__ l1w,        // [V,25,NE]
    const float* __restrict__ l1b,        // [V,25]
    float* __restrict__ A1t) {            // [V*25][B]
  int i = blockIdx.x >> 7;
  int b = blockIdx.x & 127;
  int t = threadIdx.x;

  __shared__ float sS[3][P], sY[3][P];    // 12 KB SoA (s,y only)
  __shared__ float slb[3][NE];
  __shared__ float hn[NE];

  int d0 = (i + V - 1) & (V - 1), d1 = i, d2 = (i + 1) & (V - 1);
  int len0 = lengths[d0 * B + b];
  int len1 = lengths[d1 * B + b];
  int len2 = lengths[d2 * B + b];

  for (int u = t; u < 3 * P; u += 256) {
    int jj = u >> 9;
    int pp = u & (P - 1);
    int d   = (jj == 0) ? d0 : (jj == 1) ? d1 : d2;
    int len = (jj == 0) ? len0 : (jj == 1) ? len1 : len2;
    float2 q = pts2[((size_t)d * B + b) * P + pp];
    float s = (q.x + q.y) * INV_SQRT2;
    float y = (q.y - q.x) * INV_SQRT2;
    if (y <= NU) y = __logf(fmaxf(y, 1e-12f) * 10.0f) + NU;
    if (pp >= len) { s = 1e9f; y = 1e9f; }  // exp2 -> 0 exactly
    sS[jj][pp] = s;
    sY[jj][pp] = y;
  }

  // wave-uniform (j,n) mapping
  int w = t >> 6, l = t & 63;
  int j, n;
  bool active;
  if (w < 3) {
    j = w;
    n = l;
    active = true;
  } else {
    active = (l < 33);
    int jl = l / 11;
    if (!active) jl = 2;
    j = jl;
    n = active ? (64 + (l - jl * 11)) : 74;
  }

  int ci = (i * NE + n) * 2;
  float a  = sharp[ci],   c  = sharp[ci + 1];
  float cs = centers[ci], cy = centers[ci + 1];
  float nA = -a * L2E;
  float nC = -c * L2E;
  float Bsc = 2.0f * a * cs * L2E;
  float Byc = 2.0f * c * cy * L2E;
  float nD = -(a * cs * cs + c * cy * cy) * L2E;
  v4f nA4 = {nA, nA, nA, nA}, nC4 = {nC, nC, nC, nC};
  v4f Bs4 = {Bsc, Bsc, Bsc, Bsc}, By4 = {Byc, Byc, Byc, Byc};
  v4f nD4 = {nD, nD, nD, nD};

  int mx = (w == 0) ? len0
         : (w == 1) ? len1
         : (w == 2) ? len2 : max(len0, max(len1, len2));
  int trip = (mx + 7) & ~7;

  __syncthreads();

  float ac0 = 0.f, ac1 = 0.f, ac2 = 0.f, ac3 = 0.f;
  float ac4 = 0.f, ac5 = 0.f, ac6 = 0.f, ac7 = 0.f;
  for (int p = 0; p < trip; p += 8) {
    v4f Sa = *(const v4f*)&sS[j][p], Sb = *(const v4f*)&sS[j][p + 4];
    v4f Ya = *(const v4f*)&sY[j][p], Yb = *(const v4f*)&sY[j][p + 4];
    v4f ua = v4fma(nA4, Sa, Bs4), ub = v4fma(nA4, Sb, Bs4);
    v4f va = v4fma(nC4, Ya, By4), vb = v4fma(nC4, Yb, By4);
    v4f ta = v4fma(Sa, ua, nD4),  tb = v4fma(Sb, ub, nD4);
    v4f argA = v4fma(Ya, va, ta), argB = v4fma(Yb, vb, tb);
    ac0 += fast_exp2(argA.x);
    ac1 += fast_exp2(argA.y);
    ac2 += fast_exp2(argA.z);
    ac3 += fast_exp2(argA.w);
    ac4 += fast_exp2(argB.x);
    ac5 += fast_exp2(argB.y);
    ac6 += fast_exp2(argB.z);
    ac7 += fast_exp2(argB.w);
  }
  float accv = ((ac0 + ac1) + (ac2 + ac3)) + ((ac4 + ac5) + (ac6 + ac7));

  if (active) slb[j][n] = accv;
  __syncthreads();

  if (t < NE) {
    float s0 = slb[0][t], s1 = slb[1][t], s2 = slb[2][t];
    float a0 = 0, a1 = 0, a2 = 0, a3 = 0;
#pragma unroll
    for (int f = 0; f < 16; ++f) {
      float w0 = c1w[(i * 16 + f) * 3 + 0];
      float w1 = c1w[(i * 16 + f) * 3 + 1];
      float w2 = c1w[(i * 16 + f) * 3 + 2];
      float h1 = fmaf(w0, s0, fmaf(w1, s1, w2 * s2));
      a0 = fmaf(c2w[(i * 4 + 0) * 16 + f], h1, a0);
      a1 = fmaf(c2w[(i * 4 + 1) * 16 + f], h1, a1);
      a2 = fmaf(c2w[(i * 4 + 2) * 16 + f], h1, a2);
      a3 = fmaf(c2w[(i * 4 + 3) * 16 + f], h1, a3);
    }
    hn[t] = fmaxf(fmaxf(a0, a1), fmaxf(a2, a3));
  }
  __syncthreads();

  if (t < 25) {
    float acc = l1b[i * 25 + t];
    const float* wgt = l1w + ((size_t)i * 25 + t) * NE;
#pragma unroll 5
    for (int m = 0; m < NE; ++m) acc = fmaf(wgt[m], hn[m], acc);
    A1t[((size_t)(i * 25 + t)) * B + b] = acc;
  }
}

// ---------------------------------------------------------------------------
// KB: bn1 (redundant per-block batch stats from L2) + l2(25x25)+relu + fc1.
// ---------------------------------------------------------------------------
__global__ __launch_bounds__(256) void k_tail1(
    const float* __restrict__ A1t, const float* __restrict__ g1,
    const float* __restrict__ b1, const float* __restrict__ l2w,
    const float* __restrict__ l2b, const float* __restrict__ fc1w,
    const float* __restrict__ fc1b, float* __restrict__ Yt) {
  int b = blockIdx.x;
  int t = threadIdx.x;
  __shared__ float xin[200];
  __shared__ float Xl[200];

  if (t < 200) {
    const float4* col = (const float4*)(A1t + (size_t)t * B);
    float4 s4 = {0, 0, 0, 0}, q4 = {0, 0, 0, 0};
#pragma unroll
    for (int u = 0; u < B / 4; ++u) {
      float4 v = col[u];
      s4.x += v.x; s4.y += v.y; s4.z += v.z; s4.w += v.w;
      q4.x = fmaf(v.x, v.x, q4.x); q4.y = fmaf(v.y, v.y, q4.y);
      q4.z = fmaf(v.z, v.z, q4.z); q4.w = fmaf(v.w, v.w, q4.w);
    }
    float s = (s4.x + s4.y) + (s4.z + s4.w);
    float q = (q4.x + q4.y) + (q4.z + q4.w);
    float m = s * (1.0f / B);
    float var = q * (1.0f / B) - m * m;
    float r = rsqrtf(var + EPS);
    float v = A1t[(size_t)t * B + b];
    xin[t] = (v - m) * r * g1[t] + b1[t];
  }
  __syncthreads();
  if (t < 200) {
    int i = t / 25;
    float acc = l2b[t];
    const float* w = l2w + (size_t)t * 25;
    const float* x = xin + i * 25;
#pragma unroll
    for (int jj = 0; jj < 25; ++jj) acc = fmaf(w[jj], x[jj], acc);
    Xl[t] = fmaxf(acc, 0.0f);
  }
  __syncthreads();
  if (t < 100) {
    float acc = fc1b[t];
    const float* w = fc1w + (size_t)t * 200;
#pragma unroll 8
    for (int q = 0; q < 200; ++q) acc = fmaf(w[q], Xl[q], acc);
    Yt[(size_t)t * B + b] = acc;
  }
}

// ---------------------------------------------------------------------------
// KC: bn2 (redundant per-block stats) + fc2 -> out[B,70]
// ---------------------------------------------------------------------------
__global__ __launch_bounds__(128) void k_tail2(
    const float* __restrict__ Yt, const float* __restrict__ g2,
    const float* __restrict__ b2, const float* __restrict__ fc2w,
    const float* __restrict__ fc2b, float* __restrict__ out) {
  int b = blockIdx.x;
  int t = threadIdx.x;
  __shared__ float yin[100];
  if (t < 100) {
    const float4* col = (const float4*)(Yt + (size_t)t * B);
    float4 s4 = {0, 0, 0, 0}, q4 = {0, 0, 0, 0};
#pragma unroll
    for (int u = 0; u < B / 4; ++u) {
      float4 v = col[u];
      s4.x += v.x; s4.y += v.y; s4.z += v.z; s4.w += v.w;
      q4.x = fmaf(v.x, v.x, q4.x); q4.y = fmaf(v.y, v.y, q4.y);
      q4.z = fmaf(v.z, v.z, q4.z); q4.w = fmaf(v.w, v.w, q4.w);
    }
    float s = (s4.x + s4.y) + (s4.z + s4.w);
    float q = (q4.x + q4.y) + (q4.z + q4.w);
    float m = s * (1.0f / B);
    float var = q * (1.0f / B) - m * m;
    float r = rsqrtf(var + EPS);
    float v = Yt[(size_t)t * B + b];
    yin[t] = (v - m) * r * g2[t] + b2[t];
  }
  __syncthreads();
  if (t < 70) {
    float acc = fc2b[t];
    const float* w = fc2w + (size_t)t * 100;
#pragma unroll 4
    for (int m = 0; m < 100; ++m) acc = fmaf(w[m], yin[m], acc);
    out[(size_t)b * 70 + t] = acc;
  }
}

// ---------------------------------------------------------------------------
extern "C" void kernel_launch(void* const* d_in, const int* in_sizes, int n_in,
                              void* d_out, int out_size, void* d_ws, size_t ws_size,
                              hipStream_t stream) {
  const float2* pts2   = (const float2*)d_in[0];
  const int*   lengths = (const int*)d_in[1];
  const float* centers = (const float*)d_in[2];
  const float* sharp   = (const float*)d_in[3];
  const float* c1w     = (const float*)d_in[4];
  const float* c2w     = (const float*)d_in[5];
  const float* l1w     = (const float*)d_in[6];
  const float* l1b     = (const float*)d_in[7];
  const float* bn1g    = (const float*)d_in[8];
  const float* bn1b    = (const float*)d_in[9];
  const float* l2w     = (const float*)d_in[10];
  const float* l2b     = (const float*)d_in[11];
  const float* fc1w    = (const float*)d_in[12];
  const float* fc1b    = (const float*)d_in[13];
  const float* fbn_g   = (const float*)d_in[14];
  const float* fbn_b   = (const float*)d_in[15];
  const float* fc2w    = (const float*)d_in[16];
  const float* fc2b    = (const float*)d_in[17];
  float* out = (float*)d_out;

  float* A1t = (float*)d_ws;          // [200][128]
  float* Yt  = A1t + 200 * B;         // [100][128]

  // MEASUREMENT: k_structure launched twice (idempotent). Delta vs R8 total
  // (44.16 us) = one k_structure duration + one launch overhead.
  k_structure<<<dim3(V * B), dim3(256), 0, stream>>>(
      pts2, lengths, centers, sharp, c1w, c2w, l1w, l1b, A1t);
  k_structure<<<dim3(V * B), dim3(256), 0, stream>>>(
      pts2, lengths, centers, sharp, c1w, c2w, l1w, l1b, A1t);
  k_tail1<<<dim3(B), dim3(256), 0, stream>>>(
      A1t, bn1g, bn1b, l2w, l2b, fc1w, fc1b, Yt);
  k_tail2<<<dim3(B), dim3(128), 0, stream>>>(
      Yt, fbn_g, fbn_b, fc2w, fc2b, out);
}

// Round 11
// 45.207 us; speedup vs baseline: 2.6917x; 1.5098x over previous
//
#include <hip/hip_runtime.h>
#include <math.h>

#define V 8
#define B 128
#define P 512
#define NE 75

static constexpr float NU = 0.1f;
static constexpr float EPS = 1e-5f;
static constexpr float INV_SQRT2 = 0.70710678118654752440f;
static constexpr float L2E = 1.4426950408889634f;   // log2(e)
static constexpr float LN2 = 0.69314718055994530942f;

typedef float v4f __attribute__((ext_vector_type(4)));

// Guaranteed single-instruction transcendentals (R11: rule out OCML libcall).
__device__ __forceinline__ float fast_exp2(float x) {
  float r;
  asm("v_exp_f32 %0, %1" : "=v"(r) : "v"(x));
  return r;
}
__device__ __forceinline__ float fast_log2(float x) {
  float r;
  asm("v_log_f32 %0, %1" : "=v"(r) : "v"(x));
  return r;
}

__device__ __forceinline__ v4f v4fma(v4f a, v4f b, v4f c) {
#if __has_builtin(__builtin_elementwise_fma)
  return __builtin_elementwise_fma(a, b, c);
#else
  v4f r;
  r.x = fmaf(a.x, b.x, c.x); r.y = fmaf(a.y, b.y, c.y);
  r.z = fmaf(a.z, b.z, c.z); r.w = fmaf(a.w, b.w, c.w);
  return r;
#endif
}

// ---------------------------------------------------------------------------
// KA (hot): transform + masked Gaussian sums + conv1->conv2->max -> l1.
// R11 structure: 512 threads = 8 waves. 450 work items = 225 (j,n) x 2
// point-halves (even/odd chunks of 8), so no single wave owns the longest
// direction's full trip (old SIMD3 long-pole). Partials combined in LDS.
// Masked points staged 1e9 -> exp2 -> 0; chunk overshoot lands on masked
// points (p <= 504 always, no OOB).
// ---------------------------------------------------------------------------
__global__ __launch_bounds__(512, 2) void k_structure(
    const float2* __restrict__ pts2,      // [V,B,P] (birth,death)
    const int* __restrict__ lengths,      // [V,B]
    const float* __restrict__ centers,    // [V,NE,2] (transformed)
    const float* __restrict__ sharp,      // [V,NE,2]
    const float* __restrict__ c1w,        // [V,16,3]
    const float* __restrict__ c2w,        // [V,4,16]
    const float* __restrict__ l1w,        // [V,25,NE]
    const float* __restrict__ l1b,        // [V,25]
    float* __restrict__ A1t) {            // [V*25][B]
  int i = blockIdx.x >> 7;
  int b = blockIdx.x & 127;
  int t = threadIdx.x;  // 0..511

  __shared__ float sS[3][P], sY[3][P];    // 12 KB
  __shared__ float part[450];
  __shared__ float slb[3][NE];
  __shared__ float hn[NE];

  int d0 = (i + V - 1) & (V - 1), d1 = i, d2 = (i + 1) & (V - 1);
  int len0 = lengths[d0 * B + b];
  int len1 = lengths[d1 * B + b];
  int len2 = lengths[d2 * B + b];

  // ---- staging: 1536 points, 3 per thread ----
  for (int u = t; u < 3 * P; u += 512) {
    int jj = u >> 9;
    int pp = u & (P - 1);
    int d   = (jj == 0) ? d0 : (jj == 1) ? d1 : d2;
    int len = (jj == 0) ? len0 : (jj == 1) ? len1 : len2;
    float2 q = pts2[((size_t)d * B + b) * P + pp];
    float s = (q.x + q.y) * INV_SQRT2;
    float y = (q.y - q.x) * INV_SQRT2;
    if (y <= NU) y = fast_log2(fmaxf(y, 1e-12f) * 10.0f) * LN2 + NU;
    if (pp >= len) { s = 1e9f; y = 1e9f; }  // exp2 -> 0 exactly
    sS[jj][pp] = s;
    sY[jj][pp] = y;
  }

  // ---- work-item mapping: q in [0,450): half = q>=225, (j,n) from q%225 ----
  bool active = (t < 450);
  int q = active ? t : 449;
  int half = (q >= 225) ? 1 : 0;
  int jn = q - half * 225;
  int j = jn / 75;           // 0..2 (compiler: magic mul)
  int n = jn - j * 75;

  int ci = (i * NE + n) * 2;
  float a  = sharp[ci],   c  = sharp[ci + 1];
  float cs = centers[ci], cy = centers[ci + 1];
  float nA = -a * L2E;
  float nC = -c * L2E;
  float Bsc = 2.0f * a * cs * L2E;
  float Byc = 2.0f * c * cy * L2E;
  float nD = -(a * cs * cs + c * cy * cy) * L2E;
  v4f nA4 = {nA, nA, nA, nA}, nC4 = {nC, nC, nC, nC};
  v4f Bs4 = {Bsc, Bsc, Bsc, Bsc}, By4 = {Byc, Byc, Byc, Byc};
  v4f nD4 = {nD, nD, nD, nD};

  // wave-max length over lanes' own directions -> uniform chunk count
  int mylen = (j == 0) ? len0 : (j == 1) ? len1 : len2;
  int lmax = mylen;
#pragma unroll
  for (int o = 32; o; o >>= 1) lmax = max(lmax, __shfl_xor(lmax, o));
  int nc8 = (lmax + 7) >> 3;  // chunks of 8 points

  __syncthreads();

  // ---- hot loop: this lane does chunks c+half for even c (its half) ----
  float ac0 = 0.f, ac1 = 0.f, ac2 = 0.f, ac3 = 0.f;
  float ac4 = 0.f, ac5 = 0.f, ac6 = 0.f, ac7 = 0.f;
  for (int cch = 0; cch < nc8; cch += 2) {
    int p = (cch + half) * 8;   // <= 504 always (no OOB; overshoot is masked)
    v4f Sa = *(const v4f*)&sS[j][p], Sb = *(const v4f*)&sS[j][p + 4];
    v4f Ya = *(const v4f*)&sY[j][p], Yb = *(const v4f*)&sY[j][p + 4];
    v4f ua = v4fma(nA4, Sa, Bs4), ub = v4fma(nA4, Sb, Bs4);
    v4f va = v4fma(nC4, Ya, By4), vb = v4fma(nC4, Yb, By4);
    v4f ta = v4fma(Sa, ua, nD4),  tb = v4fma(Sb, ub, nD4);
    v4f argA = v4fma(Ya, va, ta), argB = v4fma(Yb, vb, tb);
    ac0 += fast_exp2(argA.x);
    ac1 += fast_exp2(argA.y);
    ac2 += fast_exp2(argA.z);
    ac3 += fast_exp2(argA.w);
    ac4 += fast_exp2(argB.x);
    ac5 += fast_exp2(argB.y);
    ac6 += fast_exp2(argB.z);
    ac7 += fast_exp2(argB.w);
  }
  float accv = ((ac0 + ac1) + (ac2 + ac3)) + ((ac4 + ac5) + (ac6 + ac7));

  if (active) part[t] = accv;
  __syncthreads();

  // ---- combine halves ----
  if (t < 225) {
    int jj = t / 75, nn = t - jj * 75;
    slb[jj][nn] = part[t] + part[t + 225];
  }
  __syncthreads();

  // ---- head: conv1(3->16) -> conv2(16->4) -> channel-max ----
  if (t < NE) {
    float s0 = slb[0][t], s1 = slb[1][t], s2 = slb[2][t];
    float a0 = 0, a1 = 0, a2 = 0, a3 = 0;
#pragma unroll
    for (int f = 0; f < 16; ++f) {
      float w0 = c1w[(i * 16 + f) * 3 + 0];
      float w1 = c1w[(i * 16 + f) * 3 + 1];
      float w2 = c1w[(i * 16 + f) * 3 + 2];
      float h1 = fmaf(w0, s0, fmaf(w1, s1, w2 * s2));
      a0 = fmaf(c2w[(i * 4 + 0) * 16 + f], h1, a0);
      a1 = fmaf(c2w[(i * 4 + 1) * 16 + f], h1, a1);
      a2 = fmaf(c2w[(i * 4 + 2) * 16 + f], h1, a2);
      a3 = fmaf(c2w[(i * 4 + 3) * 16 + f], h1, a3);
    }
    hn[t] = fmaxf(fmaxf(a0, a1), fmaxf(a2, a3));
  }
  __syncthreads();

  if (t < 25) {
    float acc = l1b[i * 25 + t];
    const float* wgt = l1w + ((size_t)i * 25 + t) * NE;
#pragma unroll 5
    for (int m = 0; m < NE; ++m) acc = fmaf(wgt[m], hn[m], acc);
    A1t[((size_t)(i * 25 + t)) * B + b] = acc;
  }
}

// ---------------------------------------------------------------------------
// KB: bn1 (redundant per-block batch stats from L2) + l2(25x25)+relu + fc1.
// ---------------------------------------------------------------------------
__global__ __launch_bounds__(256) void k_tail1(
    const float* __restrict__ A1t, const float* __restrict__ g1,
    const float* __restrict__ b1, const float* __restrict__ l2w,
    const float* __restrict__ l2b, const float* __restrict__ fc1w,
    const float* __restrict__ fc1b, float* __restrict__ Yt) {
  int b = blockIdx.x;
  int t = threadIdx.x;
  __shared__ float xin[200];
  __shared__ float Xl[200];

  if (t < 200) {
    const float4* col = (const float4*)(A1t + (size_t)t * B);
    float4 s4 = {0, 0, 0, 0}, q4 = {0, 0, 0, 0};
#pragma unroll
    for (int u = 0; u < B / 4; ++u) {
      float4 v = col[u];
      s4.x += v.x; s4.y += v.y; s4.z += v.z; s4.w += v.w;
      q4.x = fmaf(v.x, v.x, q4.x); q4.y = fmaf(v.y, v.y, q4.y);
      q4.z = fmaf(v.z, v.z, q4.z); q4.w = fmaf(v.w, v.w, q4.w);
    }
    float s = (s4.x + s4.y) + (s4.z + s4.w);
    float q = (q4.x + q4.y) + (q4.z + q4.w);
    float m = s * (1.0f / B);
    float var = q * (1.0f / B) - m * m;
    float r = rsqrtf(var + EPS);
    float v = A1t[(size_t)t * B + b];
    xin[t] = (v - m) * r * g1[t] + b1[t];
  }
  __syncthreads();
  if (t < 200) {
    int i = t / 25;
    float acc = l2b[t];
    const float* w = l2w + (size_t)t * 25;
    const float* x = xin + i * 25;
#pragma unroll
    for (int jj = 0; jj < 25; ++jj) acc = fmaf(w[jj], x[jj], acc);
    Xl[t] = fmaxf(acc, 0.0f);
  }
  __syncthreads();
  if (t < 100) {
    float acc = fc1b[t];
    const float* w = fc1w + (size_t)t * 200;
#pragma unroll 8
    for (int q = 0; q < 200; ++q) acc = fmaf(w[q], Xl[q], acc);
    Yt[(size_t)t * B + b] = acc;
  }
}

// ---------------------------------------------------------------------------
// KC: bn2 (redundant per-block stats) + fc2 -> out[B,70]
// ---------------------------------------------------------------------------
__global__ __launch_bounds__(128) void k_tail2(
    const float* __restrict__ Yt, const float* __restrict__ g2,
    const float* __restrict__ b2, const float* __restrict__ fc2w,
    const float* __restrict__ fc2b, float* __restrict__ out) {
  int b = blockIdx.x;
  int t = threadIdx.x;
  __shared__ float yin[100];
  if (t < 100) {
    const float4* col = (const float4*)(Yt + (size_t)t * B);
    float4 s4 = {0, 0, 0, 0}, q4 = {0, 0, 0, 0};
#pragma unroll
    for (int u = 0; u < B / 4; ++u) {
      float4 v = col[u];
      s4.x += v.x; s4.y += v.y; s4.z += v.z; s4.w += v.w;
      q4.x = fmaf(v.x, v.x, q4.x); q4.y = fmaf(v.y, v.y, q4.y);
      q4.z = fmaf(v.z, v.z, q4.z); q4.w = fmaf(v.w, v.w, q4.w);
    }
    float s = (s4.x + s4.y) + (s4.z + s4.w);
    float q = (q4.x + q4.y) + (q4.z + q4.w);
    float m = s * (1.0f / B);
    float var = q * (1.0f / B) - m * m;
    float r = rsqrtf(var + EPS);
    float v = Yt[(size_t)t * B + b];
    yin[t] = (v - m) * r * g2[t] + b2[t];
  }
  __syncthreads();
  if (t < 70) {
    float acc = fc2b[t];
    const float* w = fc2w + (size_t)t * 100;
#pragma unroll 4
    for (int m = 0; m < 100; ++m) acc = fmaf(w[m], yin[m], acc);
    out[(size_t)b * 70 + t] = acc;
  }
}

// ---------------------------------------------------------------------------
extern "C" void kernel_launch(void* const* d_in, const int* in_sizes, int n_in,
                              void* d_out, int out_size, void* d_ws, size_t ws_size,
                              hipStream_t stream) {
  const float2* pts2   = (const float2*)d_in[0];
  const int*   lengths = (const int*)d_in[1];
  const float* centers = (const float*)d_in[2];
  const float* sharp   = (const float*)d_in[3];
  const float* c1w     = (const float*)d_in[4];
  const float* c2w     = (const float*)d_in[5];
  const float* l1w     = (const float*)d_in[6];
  const float* l1b     = (const float*)d_in[7];
  const float* bn1g    = (const float*)d_in[8];
  const float* bn1b    = (const float*)d_in[9];
  const float* l2w     = (const float*)d_in[10];
  const float* l2b     = (const float*)d_in[11];
  const float* fc1w    = (const float*)d_in[12];
  const float* fc1b    = (const float*)d_in[13];
  const float* fbn_g   = (const float*)d_in[14];
  const float* fbn_b   = (const float*)d_in[15];
  const float* fc2w    = (const float*)d_in[16];
  const float* fc2b    = (const float*)d_in[17];
  float* out = (float*)d_out;

  float* A1t = (float*)d_ws;          // [200][128]
  float* Yt  = A1t + 200 * B;         // [100][128]

  k_structure<<<dim3(V * B), dim3(512), 0, stream>>>(
      pts2, lengths, centers, sharp, c1w, c2w, l1w, l1b, A1t);
  k_tail1<<<dim3(B), dim3(256), 0, stream>>>(
      A1t, bn1g, bn1b, l2w, l2b, fc1w, fc1b, Yt);
  k_tail2<<<dim3(B), dim3(128), 0, stream>>>(
      Yt, fbn_g, fbn_b, fc2w, fc2b, out);
}

// Round 12
// 42.873 us; speedup vs baseline: 2.8383x; 1.0545x over previous
//
#include <hip/hip_runtime.h>
#include <math.h>

#define V 8
#define B 128
#define P 512
#define PPAD 528   // P + 16: prefetch overread pad
#define NE 75

static constexpr float NU = 0.1f;
static constexpr float EPS = 1e-5f;
static constexpr float INV_SQRT2 = 0.70710678118654752440f;
static constexpr float L2E = 1.4426950408889634f;  // log2(e)

typedef float v4f __attribute__((ext_vector_type(4)));

__device__ __forceinline__ float fast_exp2(float x) {
#if __has_builtin(__builtin_amdgcn_exp2f)
  return __builtin_amdgcn_exp2f(x);
#else
  return exp2f(x);
#endif
}

__device__ __forceinline__ v4f v4fma(v4f a, v4f b, v4f c) {
#if __has_builtin(__builtin_elementwise_fma)
  return __builtin_elementwise_fma(a, b, c);
#else
  v4f r;
  r.x = fmaf(a.x, b.x, c.x); r.y = fmaf(a.y, b.y, c.y);
  r.z = fmaf(a.z, b.z, c.z); r.w = fmaf(a.w, b.w, c.w);
  return r;
#endif
}

// ---------------------------------------------------------------------------
// KA (hot): transform + masked Gaussian sums + conv1->conv2->max -> l1.
// R12 CHANGE (single mechanism): 2-deep register software pipeline in the
// hot loop — prefetch the NEXT 16 points' (s,y) while computing the current
// 16 — so the per-iteration ds_read -> s_waitcnt lgkmcnt -> use stall chain
// is broken (the waitcnt for iter k+1's loads retires during iter k's
// ~100-cycle compute body). LDS rows padded to 528 so the last prefetch
// overread is legal (values rotated but never consumed).
// Everything else identical to R8 (44.16 us baseline).
// ---------------------------------------------------------------------------
__global__ __launch_bounds__(256, 4) void k_structure(
    const float2* __restrict__ pts2,      // [V,B,P] (birth,death)
    const int* __restrict__ lengths,      // [V,B]
    const float* __restrict__ centers,    // [V,NE,2] (transformed)
    const float* __restrict__ sharp,      // [V,NE,2]
    const float* __restrict__ c1w,        // [V,16,3]
    const float* __restrict__ c2w,        // [V,4,16]
    const float* __restrict__ l1w,        // [V,25,NE]
    const float* __restrict__ l1b,        // [V,25]
    float* __restrict__ A1t) {            // [V*25][B]
  int i = blockIdx.x >> 7;
  int b = blockIdx.x & 127;
  int t = threadIdx.x;

  __shared__ float sS[3][PPAD], sY[3][PPAD];   // 12.7 KB
  __shared__ float slb[3][NE];
  __shared__ float hn[NE];

  int d0 = (i + V - 1) & (V - 1), d1 = i, d2 = (i + 1) & (V - 1);
  int len0 = lengths[d0 * B + b];
  int len1 = lengths[d1 * B + b];
  int len2 = lengths[d2 * B + b];

  // ---- staging: load+transform 3 directions x 512 points ----
  for (int u = t; u < 3 * P; u += 256) {
    int jj = u >> 9;
    int pp = u & (P - 1);
    int d   = (jj == 0) ? d0 : (jj == 1) ? d1 : d2;
    int len = (jj == 0) ? len0 : (jj == 1) ? len1 : len2;
    float2 q = pts2[((size_t)d * B + b) * P + pp];
    float s = (q.x + q.y) * INV_SQRT2;
    float y = (q.y - q.x) * INV_SQRT2;
    if (y <= NU) y = __logf(fmaxf(y, 1e-12f) * 10.0f) + NU;
    if (pp >= len) { s = 1e9f; y = 1e9f; }  // exp2 -> 0 exactly
    sS[jj][pp] = s;
    sY[jj][pp] = y;
  }

  // wave-uniform (j,n) mapping (R7): one j per full wave -> broadcast reads
  int w = t >> 6, l = t & 63;
  int j, n;
  bool active;
  if (w < 3) {
    j = w;
    n = l;
    active = true;
  } else {
    active = (l < 33);
    int jl = l / 11;
    if (!active) jl = 2;
    j = jl;
    n = active ? (64 + (l - jl * 11)) : 74;
  }

  int ci = (i * NE + n) * 2;
  float a  = sharp[ci],   c  = sharp[ci + 1];
  float cs = centers[ci], cy = centers[ci + 1];
  float nA = -a * L2E;
  float nC = -c * L2E;
  float Bsc = 2.0f * a * cs * L2E;
  float Byc = 2.0f * c * cy * L2E;
  float nD = -(a * cs * cs + c * cy * cy) * L2E;
  v4f nA4 = {nA, nA, nA, nA}, nC4 = {nC, nC, nC, nC};
  v4f Bs4 = {Bsc, Bsc, Bsc, Bsc}, By4 = {Byc, Byc, Byc, Byc};
  v4f nD4 = {nD, nD, nD, nD};

  int mx = (w == 0) ? len0
         : (w == 1) ? len1
         : (w == 2) ? len2 : max(len0, max(len1, len2));
  int trip = (mx + 15) & ~15;   // 16 points per iteration

  __syncthreads();

  const float* Sj = sS[j];
  const float* Yj = sY[j];

  // ---- 2-deep pipelined hot loop ----
  v4f cs0 = *(const v4f*)&Sj[0],  cs1 = *(const v4f*)&Sj[4];
  v4f cs2 = *(const v4f*)&Sj[8],  cs3 = *(const v4f*)&Sj[12];
  v4f cy0 = *(const v4f*)&Yj[0],  cy1 = *(const v4f*)&Yj[4];
  v4f cy2 = *(const v4f*)&Yj[8],  cy3 = *(const v4f*)&Yj[12];

  float ac0 = 0.f, ac1 = 0.f, ac2 = 0.f, ac3 = 0.f;
  float ac4 = 0.f, ac5 = 0.f, ac6 = 0.f, ac7 = 0.f;
  for (int p = 0; p < trip; p += 16) {
    // prefetch next 16 (pad makes overread legal; unused past the end)
    v4f ns0 = *(const v4f*)&Sj[p + 16], ns1 = *(const v4f*)&Sj[p + 20];
    v4f ns2 = *(const v4f*)&Sj[p + 24], ns3 = *(const v4f*)&Sj[p + 28];
    v4f ny0 = *(const v4f*)&Yj[p + 16], ny1 = *(const v4f*)&Yj[p + 20];
    v4f ny2 = *(const v4f*)&Yj[p + 24], ny3 = *(const v4f*)&Yj[p + 28];

    // compute current 16: arg = y*(nC*y+By) + (s*(nA*s+Bs) + nD)
    v4f u0 = v4fma(nA4, cs0, Bs4), u1 = v4fma(nA4, cs1, Bs4);
    v4f u2 = v4fma(nA4, cs2, Bs4), u3 = v4fma(nA4, cs3, Bs4);
    v4f v0 = v4fma(nC4, cy0, By4), v1 = v4fma(nC4, cy1, By4);
    v4f v2 = v4fma(nC4, cy2, By4), v3 = v4fma(nC4, cy3, By4);
    v4f t0 = v4fma(cs0, u0, nD4),  t1 = v4fma(cs1, u1, nD4);
    v4f t2 = v4fma(cs2, u2, nD4),  t3 = v4fma(cs3, u3, nD4);
    v4f a0 = v4fma(cy0, v0, t0),   a1 = v4fma(cy1, v1, t1);
    v4f a2 = v4fma(cy2, v2, t2),   a3 = v4fma(cy3, v3, t3);
    ac0 += fast_exp2(a0.x); ac1 += fast_exp2(a0.y);
    ac2 += fast_exp2(a0.z); ac3 += fast_exp2(a0.w);
    ac4 += fast_exp2(a1.x); ac5 += fast_exp2(a1.y);
    ac6 += fast_exp2(a1.z); ac7 += fast_exp2(a1.w);
    ac0 += fast_exp2(a2.x); ac1 += fast_exp2(a2.y);
    ac2 += fast_exp2(a2.z); ac3 += fast_exp2(a2.w);
    ac4 += fast_exp2(a3.x); ac5 += fast_exp2(a3.y);
    ac6 += fast_exp2(a3.z); ac7 += fast_exp2(a3.w);

    cs0 = ns0; cs1 = ns1; cs2 = ns2; cs3 = ns3;
    cy0 = ny0; cy1 = ny1; cy2 = ny2; cy3 = ny3;
  }
  float accv = ((ac0 + ac1) + (ac2 + ac3)) + ((ac4 + ac5) + (ac6 + ac7));

  if (active) slb[j][n] = accv;
  __syncthreads();

  // ---- head: conv1(3->16) -> conv2(16->4) -> channel-max ----
  if (t < NE) {
    float s0 = slb[0][t], s1 = slb[1][t], s2 = slb[2][t];
    float a0 = 0, a1 = 0, a2 = 0, a3 = 0;
#pragma unroll
    for (int f = 0; f < 16; ++f) {
      float w0 = c1w[(i * 16 + f) * 3 + 0];
      float w1 = c1w[(i * 16 + f) * 3 + 1];
      float w2 = c1w[(i * 16 + f) * 3 + 2];
      float h1 = fmaf(w0, s0, fmaf(w1, s1, w2 * s2));
      a0 = fmaf(c2w[(i * 4 + 0) * 16 + f], h1, a0);
      a1 = fmaf(c2w[(i * 4 + 1) * 16 + f], h1, a1);
      a2 = fmaf(c2w[(i * 4 + 2) * 16 + f], h1, a2);
      a3 = fmaf(c2w[(i * 4 + 3) * 16 + f], h1, a3);
    }
    hn[t] = fmaxf(fmaxf(a0, a1), fmaxf(a2, a3));
  }
  __syncthreads();

  if (t < 25) {
    float acc = l1b[i * 25 + t];
    const float* wgt = l1w + ((size_t)i * 25 + t) * NE;
#pragma unroll 5
    for (int m = 0; m < NE; ++m) acc = fmaf(wgt[m], hn[m], acc);
    A1t[((size_t)(i * 25 + t)) * B + b] = acc;
  }
}

// ---------------------------------------------------------------------------
// KB: bn1 (redundant per-block batch stats from L2) + l2(25x25)+relu + fc1.
// ---------------------------------------------------------------------------
__global__ __launch_bounds__(256) void k_tail1(
    const float* __restrict__ A1t, const float* __restrict__ g1,
    const float* __restrict__ b1, const float* __restrict__ l2w,
    const float* __restrict__ l2b, const float* __restrict__ fc1w,
    const float* __restrict__ fc1b, float* __restrict__ Yt) {
  int b = blockIdx.x;
  int t = threadIdx.x;
  __shared__ float xin[200];
  __shared__ float Xl[200];

  if (t < 200) {
    const float4* col = (const float4*)(A1t + (size_t)t * B);
    float4 s4 = {0, 0, 0, 0}, q4 = {0, 0, 0, 0};
#pragma unroll
    for (int u = 0; u < B / 4; ++u) {
      float4 v = col[u];
      s4.x += v.x; s4.y += v.y; s4.z += v.z; s4.w += v.w;
      q4.x = fmaf(v.x, v.x, q4.x); q4.y = fmaf(v.y, v.y, q4.y);
      q4.z = fmaf(v.z, v.z, q4.z); q4.w = fmaf(v.w, v.w, q4.w);
    }
    float s = (s4.x + s4.y) + (s4.z + s4.w);
    float q = (q4.x + q4.y) + (q4.z + q4.w);
    float m = s * (1.0f / B);
    float var = q * (1.0f / B) - m * m;
    float r = rsqrtf(var + EPS);
    float v = A1t[(size_t)t * B + b];
    xin[t] = (v - m) * r * g1[t] + b1[t];
  }
  __syncthreads();
  if (t < 200) {
    int i = t / 25;
    float acc = l2b[t];
    const float* w = l2w + (size_t)t * 25;
    const float* x = xin + i * 25;
#pragma unroll
    for (int jj = 0; jj < 25; ++jj) acc = fmaf(w[jj], x[jj], acc);
    Xl[t] = fmaxf(acc, 0.0f);
  }
  __syncthreads();
  if (t < 100) {
    float acc = fc1b[t];
    const float* w = fc1w + (size_t)t * 200;
#pragma unroll 8
    for (int q = 0; q < 200; ++q) acc = fmaf(w[q], Xl[q], acc);
    Yt[(size_t)t * B + b] = acc;
  }
}

// ---------------------------------------------------------------------------
// KC: bn2 (redundant per-block stats) + fc2 -> out[B,70]
// ---------------------------------------------------------------------------
__global__ __launch_bounds__(128) void k_tail2(
    const float* __restrict__ Yt, const float* __restrict__ g2,
    const float* __restrict__ b2, const float* __restrict__ fc2w,
    const float* __restrict__ fc2b, float* __restrict__ out) {
  int b = blockIdx.x;
  int t = threadIdx.x;
  __shared__ float yin[100];
  if (t < 100) {
    const float4* col = (const float4*)(Yt + (size_t)t * B);
    float4 s4 = {0, 0, 0, 0}, q4 = {0, 0, 0, 0};
#pragma unroll
    for (int u = 0; u < B / 4; ++u) {
      float4 v = col[u];
      s4.x += v.x; s4.y += v.y; s4.z += v.z; s4.w += v.w;
      q4.x = fmaf(v.x, v.x, q4.x); q4.y = fmaf(v.y, v.y, q4.y);
      q4.z = fmaf(v.z, v.z, q4.z); q4.w = fmaf(v.w, v.w, q4.w);
    }
    float s = (s4.x + s4.y) + (s4.z + s4.w);
    float q = (q4.x + q4.y) + (q4.z + q4.w);
    float m = s * (1.0f / B);
    float var = q * (1.0f / B) - m * m;
    float r = rsqrtf(var + EPS);
    float v = Yt[(size_t)t * B + b];
    yin[t] = (v - m) * r * g2[t] + b2[t];
  }
  __syncthreads();
  if (t < 70) {
    float acc = fc2b[t];
    const float* w = fc2w + (size_t)t * 100;
#pragma unroll 4
    for (int m = 0; m < 100; ++m) acc = fmaf(w[m], yin[m], acc);
    out[(size_t)b * 70 + t] = acc;
  }
}

// ---------------------------------------------------------------------------
extern "C" void kernel_launch(void* const* d_in, const int* in_sizes, int n_in,
                              void* d_out, int out_size, void* d_ws, size_t ws_size,
                              hipStream_t stream) {
  const float2* pts2   = (const float2*)d_in[0];
  const int*   lengths = (const int*)d_in[1];
  const float* centers = (const float*)d_in[2];
  const float* sharp   = (const float*)d_in[3];
  const float* c1w     = (const float*)d_in[4];
  const float* c2w     = (const float*)d_in[5];
  const float* l1w     = (const float*)d_in[6];
  const float* l1b     = (const float*)d_in[7];
  const float* bn1g    = (const float*)d_in[8];
  const float* bn1b    = (const float*)d_in[9];
  const float* l2w     = (const float*)d_in[10];
  const float* l2b     = (const float*)d_in[11];
  const float* fc1w    = (const float*)d_in[12];
  const float* fc1b    = (const float*)d_in[13];
  const float* fbn_g   = (const float*)d_in[14];
  const float* fbn_b   = (const float*)d_in[15];
  const float* fc2w    = (const float*)d_in[16];
  const float* fc2b    = (const float*)d_in[17];
  float* out = (float*)d_out;

  float* A1t = (float*)d_ws;          // [200][128]
  float* Yt  = A1t + 200 * B;         // [100][128]

  k_structure<<<dim3(V * B), dim3(256), 0, stream>>>(
      pts2, lengths, centers, sharp, c1w, c2w, l1w, l1b, A1t);
  k_tail1<<<dim3(B), dim3(256), 0, stream>>>(
      A1t, bn1g, bn1b, l2w, l2b, fc1w, fc1b, Yt);
  k_tail2<<<dim3(B), dim3(128), 0, stream>>>(
      Yt, fbn_g, fbn_b, fc2w, fc2b, out);
}